// Round 11
// baseline (474.040 us; speedup 1.0000x reference)
//
#include <hip/hip_runtime.h>
#include <hip/hip_bf16.h>
#include <string.h>

typedef __hip_bfloat16 bf16;
typedef __attribute__((ext_vector_type(8))) short short8;
typedef __attribute__((ext_vector_type(4))) float f32x4;

#define Bsz 512
#define S3  512
#define Tsz 16
#define Cc  128
#define TT  15
#define EPSv 1e-5f

__device__ __forceinline__ float ulo(unsigned u) { return __uint_as_float(u << 16); }
__device__ __forceinline__ float uhi(unsigned u) { return __uint_as_float(u & 0xffff0000u); }
__device__ __forceinline__ unsigned short f2bu(float v) {
    bf16 h = __float2bfloat16(v);
    unsigned short u; memcpy(&u, &h, 2); return u;
}
// fast RNE bf16 (no NaN path — inputs finite)
__device__ __forceinline__ unsigned short bfr16(float a) {
    unsigned u = __float_as_uint(a);
    u = u + 0x7fffu + ((u >> 16) & 1u);
    return (unsigned short)(u >> 16);
}
__device__ __forceinline__ unsigned fpack2(float a, float b) {
    unsigned ua = __float_as_uint(a), ub = __float_as_uint(b);
    ua = ua + 0x7fffu + ((ua >> 16) & 1u);
    ub = ub + 0x7fffu + ((ub >> 16) & 1u);
    return (ua >> 16) | (ub & 0xffff0000u);
}
__device__ __forceinline__ float dot4(float4 a, float4 b) {
    return a.x*b.x + a.y*b.y + a.z*b.z + a.w*b.w;
}

// ---------------------------------------------------------------------------
// k_tpack: src (NR x NK) row-major fp32 -> float4-packed k-major (Wl for base)
// ---------------------------------------------------------------------------
__global__ __launch_bounds__(256) void k_tpack(const float* __restrict__ src,
                                               float* __restrict__ dst,
                                               int NR, int NK)
{
    __shared__ float tile[32][33];
    int k0 = blockIdx.x * 32, r0 = blockIdx.y * 32;
    int lr = threadIdx.x >> 5, lk = threadIdx.x & 31;
    for (int i = lr; i < 32; i += 8)
        tile[i][lk] = src[(size_t)(r0 + i) * NK + k0 + lk];
    __syncthreads();
    int c = threadIdx.x & 31, k4 = threadIdx.x >> 5;
    float4 v;
    v.x = tile[c][k4 * 4 + 0]; v.y = tile[c][k4 * 4 + 1];
    v.z = tile[c][k4 * 4 + 2]; v.w = tile[c][k4 * 4 + 3];
    ((float4*)dst)[(size_t)(k0 / 4 + k4) * NR + r0 + c] = v;
}

// ---------------------------------------------------------------------------
// k_cvt5: all 5 transformer weights fp32 -> bf16 in one launch (contiguous dst)
// ---------------------------------------------------------------------------
__global__ __launch_bounds__(256) void k_cvt5(
    const float* __restrict__ s0, const float* __restrict__ s1,
    const float* __restrict__ s2, const float* __restrict__ s3,
    const float* __restrict__ s4, ushort* __restrict__ dst)
{
    int i = blockIdx.x * 256 + threadIdx.x;
    if (i >= 114688) return;
    const float* src; int rel;
    if (i < 16384)      { src = s0; rel = i; }
    else if (i < 40960) { src = s1; rel = i - 16384; }
    else if (i < 49152) { src = s2; rel = i - 40960; }
    else if (i < 81920) { src = s3; rel = i - 49152; }
    else                { src = s4; rel = i - 81920; }
    float4 v = ((const float4*)src)[rel];
    ushort4 o;
    o.x = f2bu(v.x); o.y = f2bu(v.y); o.z = f2bu(v.z); o.w = f2bu(v.w);
    ((ushort4*)dst)[i] = o;
}

// ---------------------------------------------------------------------------
// k_wgnn: Wl/Wr (3 layers, 128x128 fp32) -> bf16 MFMA-fragment-major.
// grid 6: bi 0..2 = Wl layer, 3..5 = Wr layer.
// wbuf[bi*16384 + (t*4+ks)*512 + lane*8 + j], n=t*16+ml, k=ks*32+quad*8+j
// ---------------------------------------------------------------------------
__global__ __launch_bounds__(256) void k_wgnn(
    const float* __restrict__ Wl, const float* __restrict__ Wr,
    ushort* __restrict__ wbuf)
{
    int bi = blockIdx.x;
    const float* src = (bi < 3) ? Wl + bi * 16384 : Wr + (bi - 3) * 16384;
    ushort* dst = wbuf + (size_t)bi * 16384;
    for (int item = threadIdx.x; item < 2048; item += 256) {
        int f = item >> 6, lane = item & 63;
        int t = f >> 2, ks = f & 3, ml = lane & 15, q = lane >> 4;
        int n = t * 16 + ml, kb = ks * 32 + q * 8;
        const float4* wr = (const float4*)(src + n * 128 + kb);
        float4 v0 = wr[0], v1 = wr[1];
        ushort4 o0, o1;
        o0.x = f2bu(v0.x); o0.y = f2bu(v0.y); o0.z = f2bu(v0.z); o0.w = f2bu(v0.w);
        o1.x = f2bu(v1.x); o1.y = f2bu(v1.y); o1.z = f2bu(v1.z); o1.w = f2bu(v1.w);
        ushort* dp = dst + (size_t)f * 512 + lane * 8;
        *(ushort4*)dp = o0;
        *(ushort4*)(dp + 4) = o1;
    }
}

// ---------------------------------------------------------------------------
// k_torso: fused init + 3 GNN layers + pool. 1024 threads (16 waves).
// Wave = (node-group g = wv>>1: 64 nodes, channel-half = wv&1: 64 ch).
// 4 m-passes of 16 nodes; per pass only accR[4]+accL[4] = 32 acc regs live.
// LN stats combined across the two halves via st2[row][half] + 1 barrier/pass.
// ---------------------------------------------------------------------------
__global__ __launch_bounds__(1024) void k_torso(
    const int* __restrict__ xx, const float* __restrict__ ss,
    const float* __restrict__ Win, const float* __restrict__ b_in,
    const ushort* __restrict__ wbuf,
    const float4* __restrict__ WlP, const float* __restrict__ blv,
    const float* __restrict__ lng, const float* __restrict__ lnb,
    float* __restrict__ out)
{
    __shared__ ushort X[512 * 136];      // 139264 B
    __shared__ float  mC[512];           // 2 KB
    __shared__ float2 st2[512 * 2];      // 8 KB  (row stats per half)
    __shared__ float  sred[16 * 128];    // 8 KB  (init) / 16*64 used per layer
    __shared__ float  ssc[128];
    __shared__ float  sbase[128];
    __shared__ float  gln[128], bln[128];
    __shared__ float  scnt[16];
    __shared__ float  invS;

    int b = blockIdx.x, tid = threadIdx.x;
    int wv = tid >> 6, lane = tid & 63;
    int ml = lane & 15, quad = lane >> 4;
    int half = wv & 1, g = wv >> 1;      // g 0..7 -> nodes [g*64, g*64+64)

    // ================= init =================
    {
        int ph = wv, cp = lane;
        int co0 = 2 * cp, co1 = 2 * cp + 1;
        const int* x0 = xx + (size_t)b * Tsz * S3;
        float f4c = ss[b] * (1.0f / 8.0f);
        float a0 = Win[co0*5+0], a1 = Win[co0*5+1], a2 = Win[co0*5+2], a3 = Win[co0*5+3];
        float c0 = Win[co1*5+0], c1 = Win[co1*5+1], c2 = Win[co1*5+2], c3 = Win[co1*5+3];
        float ba = b_in[co0] + f4c * Win[co0*5+4];
        float bc = b_in[co1] + f4c * Win[co1*5+4];
        float sp0 = 0.f, sp1 = 0.f; int cnt = 0;
        for (int node = ph; node < S3; node += 16) {
            int f0 = x0[node];
            float m = (f0 != 0) ? 1.f : 0.f;
            float ci = (float)(node >> 6) * (1.f / 7.f);
            float cj = (float)((node >> 3) & 7) * (1.f / 7.f);
            float ck = (float)(node & 7) * (1.f / 7.f);
            float ft = (float)f0 * 0.5f;
            float v0 = ba + ci * a0 + cj * a1 + ck * a2 + ft * a3;
            float v1 = bc + ci * c0 + cj * c1 + ck * c2 + ft * c3;
            ((unsigned*)(X + node * 136))[cp] = fpack2(v0, v1);
            sp0 += v0 * m; sp1 += v1 * m;
            cnt += (f0 != 0);
            if (cp == 0) mC[node] = m;
        }
        sred[ph * 128 + co0] = sp0;
        sred[ph * 128 + co1] = sp1;
        if (cp == 0) scnt[ph] = (float)cnt;
    }
    if (tid < 128) { gln[tid] = lng[tid]; bln[tid] = lnb[tid]; }
    __syncthreads();
    if (tid == 0) {
        float n = 0.f;
#pragma unroll
        for (int k = 0; k < 16; k++) n += scnt[k];
        invS = (n > 1.f) ? 1.f / (n - 1.f) : 0.f;
    }
    __syncthreads();
    if (tid < 128) {
        float s = 0.f;
#pragma unroll
        for (int k = 0; k < 16; k++) s += sred[k * 128 + tid];
        ssc[tid] = s * invS;
    }
    __syncthreads();
    if (tid < 128) {
        float a = blv[tid];
        for (int k4 = 0; k4 < 32; k4++)
            a += dot4(*(const float4*)(ssc + k4 * 4), WlP[k4 * 384 + tid]);
        sbase[tid] = a;
    }
    __syncthreads();

    // layer-invariant LN params for this wave's 4 channel tiles
    float gg[4], be[4];
#pragma unroll
    for (int t = 0; t < 4; t++) {
        gg[t] = gln[(half * 4 + t) * 16 + ml];
        be[t] = bln[(half * 4 + t) * 16 + ml];
    }

    // ================= 3 SAGE layers =================
    float inv = invS;
    for (int l = 0; l < 3; l++) {
        const ushort* pWl = wbuf + (size_t)l * 16384 + (size_t)(half * 16) * 512 + lane * 8;
        const ushort* pWr = pWl + (size_t)3 * 16384;
        bool last = (l == 2);

        float sp[4];
#pragma unroll
        for (int t = 0; t < 4; t++) sp[t] = 0.f;

#pragma unroll
        for (int pass = 0; pass < 4; pass++) {
            int base = g * 64 + pass * 16;

            f32x4 accR[4], accL[4];
#pragma unroll
            for (int t = 0; t < 4; t++) {
                accR[t] = (f32x4){0.f, 0.f, 0.f, 0.f};
                accL[t] = (f32x4){0.f, 0.f, 0.f, 0.f};
            }

            const ushort* xr = X + (base + ml) * 136 + quad * 8;
#pragma unroll
            for (int ks = 0; ks < 4; ks++) {
                short8 a = *(const short8*)(xr + ks * 32);
#pragma unroll
                for (int t = 0; t < 4; t++) {
                    int fo = (t * 4 + ks) * 512;
                    short8 br = *(const short8*)(pWr + fo);
                    short8 bl = *(const short8*)(pWl + fo);
                    accR[t] = __builtin_amdgcn_mfma_f32_16x16x32_bf16(a, br, accR[t], 0, 0, 0);
                    accL[t] = __builtin_amdgcn_mfma_f32_16x16x32_bf16(a, bl, accL[t], 0, 0, 0);
                }
            }

            // combine + relu in-place; partial row stats over this half's 64 ch
            float bse[4];
#pragma unroll
            for (int t = 0; t < 4; t++) bse[t] = sbase[(half * 4 + t) * 16 + ml];
#pragma unroll
            for (int r = 0; r < 4; r++) {
                int row = base + quad * 4 + r;
                float s = 0.f, q = 0.f;
#pragma unroll
                for (int t = 0; t < 4; t++) {
                    float v = fmaxf(accR[t][r] - inv * accL[t][r] + bse[t], 0.f);
                    accR[t][r] = v;
                    s += v; q += v * v;
                }
#pragma unroll
                for (int off = 1; off <= 8; off <<= 1) {
                    s += __shfl_xor(s, off, 64);
                    q += __shfl_xor(q, off, 64);
                }
                if (ml == 0) st2[row * 2 + half] = make_float2(s, q);
            }
            __syncthreads();

            // apply LN, store bf16, masked channel partial sums
#pragma unroll
            for (int r = 0; r < 4; r++) {
                int row = base + quad * 4 + r;
                float2 p0 = st2[row * 2];
                float2 p1 = st2[row * 2 + 1];
                float s = p0.x + p1.x, q = p0.y + p1.y;
                float mu = s * (1.f / 128.f);
                float rs = rsqrtf(q * (1.f / 128.f) - mu * mu + EPSv);
                float mrow = mC[row];
#pragma unroll
                for (int t = 0; t < 4; t++) {
                    float y = (accR[t][r] - mu) * rs * gg[t] + be[t];
                    if (last) y *= mrow;
                    else sp[t] += y * mrow;
                    X[row * 136 + (half * 4 + t) * 16 + ml] = bfr16(y);
                }
            }
        }

        if (!last) {
#pragma unroll
            for (int t = 0; t < 4; t++) {
                sp[t] += __shfl_xor(sp[t], 16, 64);
                sp[t] += __shfl_xor(sp[t], 32, 64);
            }
            if (quad == 0) {
#pragma unroll
                for (int t = 0; t < 4; t++) sred[wv * 64 + t * 16 + ml] = sp[t];
            }
            __syncthreads();
            if (tid < 128) {
                int hf = tid >> 6, tt = (tid >> 4) & 3, mm = tid & 15;
                float s = 0.f;
#pragma unroll
                for (int k = 0; k < 8; k++)
                    s += sred[(k * 2 + hf) * 64 + tt * 16 + mm];
                ssc[tid] = s * invS;
            }
            __syncthreads();
            if (tid < 128) {
                float a = blv[(l + 1) * 128 + tid];
                for (int k4 = 0; k4 < 32; k4++)
                    a += dot4(*(const float4*)(ssc + k4 * 4), WlP[k4 * 384 + (l + 1) * 128 + tid]);
                sbase[tid] = a;
            }
            __syncthreads();
        }
    }
    __syncthreads();

    // ================= pool: slice means, 4-channel vectorized =================
    if (tid < 768) {
        int c4 = tid & 31, p = tid >> 5;
        int axis = p >> 3, idx = p & 7;
        float4 sum = {0.f, 0.f, 0.f, 0.f};
        for (int t = 0; t < 64; t++) {
            int node;
            if (axis == 0)      node = idx * 64 + t;
            else if (axis == 1) node = (t >> 3) * 64 + idx * 8 + (t & 7);
            else                node = t * 8 + idx;
            uint2 pk = *(const uint2*)(X + node * 136 + c4 * 4);
            sum.x += ulo(pk.x);
            sum.y += uhi(pk.x);
            sum.z += ulo(pk.y);
            sum.w += uhi(pk.y);
        }
        float4 o;
        o.x = sum.x * (1.f / 64.f); o.y = sum.y * (1.f / 64.f);
        o.z = sum.z * (1.f / 64.f); o.w = sum.w * (1.f / 64.f);
        *(float4*)(out + (size_t)b * 26 * Cc + p * Cc + c4 * 4) = o;
    }
}

// ---------------------------------------------------------------------------
// k_tf3: transformer, bf16 MFMA GEMMs; q/k/v stored bf16 (~50 KB LDS)
// ---------------------------------------------------------------------------
__global__ __launch_bounds__(256) void k_tf3(
    const int* __restrict__ xx, const float* __restrict__ ss,
    const ushort* __restrict__ WactB, const float* __restrict__ bact,
    const ushort* __restrict__ WqkvB, const float* __restrict__ bqkv,
    const ushort* __restrict__ WoB, const float* __restrict__ bo,
    const float* __restrict__ ln1g, const float* __restrict__ ln1b,
    const float* __restrict__ ln2g, const float* __restrict__ ln2b,
    const ushort* __restrict__ W1B, const float* __restrict__ b1v,
    const ushort* __restrict__ W2B, const float* __restrict__ b2v,
    const float* __restrict__ Wsc, const float* __restrict__ bsc,
    float* __restrict__ out)
{
    __shared__ float  As[TT * 132];
    __shared__ ushort Qs[16 * 392];
    __shared__ ushort Ab[16 * 136];
    __shared__ ushort Hs[16 * 136];
    __shared__ ushort Fs[16 * 520];
    __shared__ float  Att[60 * 16];
    __shared__ float  mu_s[TT], rs_s[TT];

    int b = blockIdx.x, tid = threadIdx.x;
    int wv = tid >> 6, lane = tid & 63;
    int ml = lane & 15, quad = lane >> 4;

    const int* xa = xx + (size_t)b * Tsz * S3 + S3;
    for (int f = tid; f < TT * 512; f += 256) {
        int t = f >> 9, s = f & 511;
        Fs[t * 520 + s] = bfr16((float)xa[t * 512 + s]);
    }
    __syncthreads();

    {
        f32x4 acc[2];
#pragma unroll
        for (int i = 0; i < 2; i++) acc[i] = (f32x4){0.f, 0.f, 0.f, 0.f};
        const ushort* ar = Fs + ml * 520 + quad * 8;
        for (int ks = 0; ks < 16; ks++) {
            short8 a = *(const short8*)(ar + ks * 32);
#pragma unroll
            for (int i = 0; i < 2; i++) {
                int n0 = (wv * 2 + i) * 16;
                short8 bfr = *(const short8*)(WactB + (size_t)(n0 + ml) * 512 + quad * 8 + ks * 32);
                acc[i] = __builtin_amdgcn_mfma_f32_16x16x32_bf16(a, bfr, acc[i], 0, 0, 0);
            }
        }
#pragma unroll
        for (int i = 0; i < 2; i++) {
            int col = (wv * 2 + i) * 16 + ml;
            float bb = bact[col];
#pragma unroll
            for (int r = 0; r < 4; r++) {
                int row = quad * 4 + r;
                if (row < TT) As[row * 132 + col] = acc[i][r] + bb;
            }
        }
    }
    __syncthreads();

    for (int l = 0; l < 2; l++) {
        const float* bq  = bqkv + l * 384;
        const float* bol = bo + l * 128;
        const float* g1  = ln1g + l * 128; const float* be1 = ln1b + l * 128;
        const float* g2  = ln2g + l * 128; const float* be2 = ln2b + l * 128;
        const float* b1l = b1v + l * 512;  const float* b2l = b2v + l * 128;

        // LN1
        for (int r = wv; r < TT; r += 4) {
            float2 v = *(const float2*)(As + r * 132 + lane * 2);
            float s = v.x + v.y, q = v.x * v.x + v.y * v.y;
            for (int off = 32; off; off >>= 1) {
                s += __shfl_xor(s, off, 64);
                q += __shfl_xor(q, off, 64);
            }
            if (lane == 0) {
                float mu = s * (1.f / 128.f);
                mu_s[r] = mu;
                rs_s[r] = rsqrtf(q * (1.f / 128.f) - mu * mu + EPSv);
            }
        }
        __syncthreads();
        for (int f = tid; f < TT * 64; f += 256) {
            int t = f >> 6, cp = f & 63;
            float mu = mu_s[t], rs = rs_s[t];
            float x0 = (As[t * 132 + 2 * cp]     - mu) * rs * g1[2 * cp]     + be1[2 * cp];
            float x1 = (As[t * 132 + 2 * cp + 1] - mu) * rs * g1[2 * cp + 1] + be1[2 * cp + 1];
            ((unsigned*)(Ab + t * 136))[cp] = fpack2(x0, x1);
        }
        __syncthreads();

        // qkv (K=128, N=384) -> Qs bf16
        {
            short8 a[4];
            const ushort* ar = Ab + ml * 136 + quad * 8;
#pragma unroll
            for (int ks = 0; ks < 4; ks++) a[ks] = *(const short8*)(ar + ks * 32);
#pragma unroll
            for (int i = 0; i < 6; i++) {
                int n0 = (wv * 6 + i) * 16;
                f32x4 acc = (f32x4){0.f, 0.f, 0.f, 0.f};
                const ushort* wb = WqkvB + (size_t)(l * 384 + n0 + ml) * 128 + quad * 8;
#pragma unroll
                for (int ks = 0; ks < 4; ks++) {
                    short8 bfr = *(const short8*)(wb + ks * 32);
                    acc = __builtin_amdgcn_mfma_f32_16x16x32_bf16(a[ks], bfr, acc, 0, 0, 0);
                }
                int col = n0 + ml;
                float bb = bq[col];
#pragma unroll
                for (int r = 0; r < 4; r++) {
                    int row = quad * 4 + r;
                    if (row < TT) Qs[row * 392 + col] = bfr16(acc[r] + bb);
                }
            }
        }
        __syncthreads();

        // attention scores + softmax
        if (tid < 60) {
            int h = tid / 15, tq = tid % 15;
            const ushort* qp = Qs + tq * 392 + h * 32;
            float sc[TT];
            float mx = -1e30f;
#pragma unroll
            for (int tk = 0; tk < TT; tk++) {
                const ushort* kp = Qs + tk * 392 + 128 + h * 32;
                float d = 0.f;
#pragma unroll
                for (int u = 0; u < 32; u += 4) {
                    uint2 qa = *(const uint2*)(qp + u);
                    uint2 ka = *(const uint2*)(kp + u);
                    d += ulo(qa.x) * ulo(ka.x) + uhi(qa.x) * uhi(ka.x)
                       + ulo(qa.y) * ulo(ka.y) + uhi(qa.y) * uhi(ka.y);
                }
                d *= 0.17677669529663689f;
                sc[tk] = d; mx = fmaxf(mx, d);
            }
            float sum = 0.f;
#pragma unroll
            for (int tk = 0; tk < TT; tk++) { float e = __expf(sc[tk] - mx); sc[tk] = e; sum += e; }
            float r = 1.f / sum;
#pragma unroll
            for (int tk = 0; tk < TT; tk++) Att[tid * 16 + tk] = sc[tk] * r;
        }
        __syncthreads();

        // o = att @ v -> Hs (bf16)
        for (int f = tid; f < TT * 64; f += 256) {
            int t = f >> 6, cp = f & 63;
            int h = cp >> 4;
            const float* ap = Att + (h * 15 + t) * 16;
            const ushort* vp = Qs + 256 + 2 * cp;
            float a0 = 0.f, a1 = 0.f;
#pragma unroll
            for (int tk = 0; tk < TT; tk++) {
                float w = ap[tk];
                unsigned pk = *(const unsigned*)(vp + tk * 392);
                a0 += w * ulo(pk);
                a1 += w * uhi(pk);
            }
            ((unsigned*)(Hs + t * 136))[cp] = fpack2(a0, a1);
        }
        __syncthreads();

        // proj + residual
        {
            short8 a[4];
            const ushort* ar = Hs + ml * 136 + quad * 8;
#pragma unroll
            for (int ks = 0; ks < 4; ks++) a[ks] = *(const short8*)(ar + ks * 32);
#pragma unroll
            for (int i = 0; i < 2; i++) {
                int n0 = (wv * 2 + i) * 16;
                f32x4 acc = (f32x4){0.f, 0.f, 0.f, 0.f};
                const ushort* wb = WoB + (size_t)(l * 128 + n0 + ml) * 128 + quad * 8;
#pragma unroll
                for (int ks = 0; ks < 4; ks++) {
                    short8 bfr = *(const short8*)(wb + ks * 32);
                    acc = __builtin_amdgcn_mfma_f32_16x16x32_bf16(a[ks], bfr, acc, 0, 0, 0);
                }
                int col = n0 + ml;
                float bb = bol[col];
#pragma unroll
                for (int r = 0; r < 4; r++) {
                    int row = quad * 4 + r;
                    if (row < TT) As[row * 132 + col] += acc[r] + bb;
                }
            }
        }
        __syncthreads();

        // LN2
        for (int r = wv; r < TT; r += 4) {
            float2 v = *(const float2*)(As + r * 132 + lane * 2);
            float s = v.x + v.y, q = v.x * v.x + v.y * v.y;
            for (int off = 32; off; off >>= 1) {
                s += __shfl_xor(s, off, 64);
                q += __shfl_xor(q, off, 64);
            }
            if (lane == 0) {
                float mu = s * (1.f / 128.f);
                mu_s[r] = mu;
                rs_s[r] = rsqrtf(q * (1.f / 128.f) - mu * mu + EPSv);
            }
        }
        __syncthreads();
        for (int f = tid; f < TT * 64; f += 256) {
            int t = f >> 6, cp = f & 63;
            float mu = mu_s[t], rs = rs_s[t];
            float x0 = (As[t * 132 + 2 * cp]     - mu) * rs * g2[2 * cp]     + be2[2 * cp];
            float x1 = (As[t * 132 + 2 * cp + 1] - mu) * rs * g2[2 * cp + 1] + be2[2 * cp + 1];
            ((unsigned*)(Ab + t * 136))[cp] = fpack2(x0, x1);
        }
        __syncthreads();

        // ff1 (K=128, N=512)
        {
            short8 a[4];
            const ushort* ar = Ab + ml * 136 + quad * 8;
#pragma unroll
            for (int ks = 0; ks < 4; ks++) a[ks] = *(const short8*)(ar + ks * 32);
#pragma unroll
            for (int i = 0; i < 8; i++) {
                int n0 = (wv * 8 + i) * 16;
                f32x4 acc = (f32x4){0.f, 0.f, 0.f, 0.f};
                const ushort* wb = W1B + (size_t)(l * 512 + n0 + ml) * 128 + quad * 8;
#pragma unroll
                for (int ks = 0; ks < 4; ks++) {
                    short8 bfr = *(const short8*)(wb + ks * 32);
                    acc = __builtin_amdgcn_mfma_f32_16x16x32_bf16(a[ks], bfr, acc, 0, 0, 0);
                }
                int col = n0 + ml;
                float bb = b1l[col];
#pragma unroll
                for (int r = 0; r < 4; r++) {
                    int row = quad * 4 + r;
                    if (row < TT) Fs[row * 520 + col] = bfr16(fmaxf(acc[r] + bb, 0.f));
                }
            }
        }
        __syncthreads();

        // ff2 + residual (K=512, N=128)
        {
            f32x4 acc[2];
#pragma unroll
            for (int i = 0; i < 2; i++) acc[i] = (f32x4){0.f, 0.f, 0.f, 0.f};
            const ushort* ar = Fs + ml * 520 + quad * 8;
            for (int ks = 0; ks < 16; ks++) {
                short8 a = *(const short8*)(ar + ks * 32);
#pragma unroll
                for (int i = 0; i < 2; i++) {
                    int n0 = (wv * 2 + i) * 16;
                    short8 bfr = *(const short8*)(W2B + (size_t)(l * 128 + n0 + ml) * 512 + quad * 8 + ks * 32);
                    acc[i] = __builtin_amdgcn_mfma_f32_16x16x32_bf16(a, bfr, acc[i], 0, 0, 0);
                }
            }
#pragma unroll
            for (int i = 0; i < 2; i++) {
                int col = (wv * 2 + i) * 16 + ml;
                float bb = b2l[col];
#pragma unroll
                for (int r = 0; r < 4; r++) {
                    int row = quad * 4 + r;
                    if (row < TT) As[row * 132 + col] += acc[i][r] + bb;
                }
            }
        }
        __syncthreads();
    }

    if (tid < 128) {
        float s = 0.f;
#pragma unroll
        for (int t = 0; t < TT; t++) s += As[t * 132 + tid];
        out[(size_t)b * 26 * Cc + 24 * Cc + tid] = s * (1.f / 15.f);
    } else if (tid < 256) {
        int co = tid - 128;
        float v = ss[b] * Wsc[co] + bsc[co];
        out[(size_t)b * 26 * Cc + 25 * Cc + co] = fmaxf(v, 0.f);
    }
}

// ---------------------------------------------------------------------------
extern "C" void kernel_launch(void* const* d_in, const int* in_sizes, int n_in,
                              void* d_out, int out_size, void* d_ws, size_t ws_size,
                              hipStream_t stream)
{
    (void)in_sizes; (void)n_in; (void)out_size; (void)ws_size;
    const int*   xx   = (const int*)d_in[0];
    const float* ss   = (const float*)d_in[1];
    const float* Win  = (const float*)d_in[2];
    const float* b_in = (const float*)d_in[3];
    const float* Wl   = (const float*)d_in[4];
    const float* bl   = (const float*)d_in[5];
    const float* Wr   = (const float*)d_in[6];
    const float* lng  = (const float*)d_in[7];
    const float* lnb  = (const float*)d_in[8];
    const float* Wqkv = (const float*)d_in[9];
    const float* bqkv = (const float*)d_in[10];
    const float* Wo   = (const float*)d_in[11];
    const float* bo   = (const float*)d_in[12];
    const float* ln1g = (const float*)d_in[13];
    const float* ln1b = (const float*)d_in[14];
    const float* ln2g = (const float*)d_in[15];
    const float* ln2b = (const float*)d_in[16];
    const float* W1   = (const float*)d_in[17];
    const float* b1   = (const float*)d_in[18];
    const float* W2   = (const float*)d_in[19];
    const float* b2   = (const float*)d_in[20];
    const float* Wact = (const float*)d_in[21];
    const float* bact = (const float*)d_in[22];
    const float* Wsc  = (const float*)d_in[23];
    const float* bsc  = (const float*)d_in[24];
    float* out = (float*)d_out;

    char* ws = (char*)d_ws;
    size_t off = 0;
    float* WlT   = (float*)(ws + off);  off += 384 * 128 * 4;
    ushort* wbuf = (ushort*)(ws + off); off += 6 * 16384 * 2;      // 196.6 KB
    ushort* WactB = (ushort*)(ws + off); off += 128 * 512 * 2;
    ushort* WqkvB = (ushort*)(ws + off); off += 768 * 128 * 2;
    ushort* WoB   = (ushort*)(ws + off); off += 256 * 128 * 2;
    ushort* W1B   = (ushort*)(ws + off); off += 1024 * 128 * 2;
    ushort* W2B   = (ushort*)(ws + off); off += 256 * 512 * 2;

    k_tpack<<<dim3(4, 12), 256, 0, stream>>>(Wl, WlT, 384, 128);
    k_cvt5<<<448, 256, 0, stream>>>(Wact, Wqkv, Wo, W1, W2, WactB);
    k_wgnn<<<6, 256, 0, stream>>>(Wl, Wr, wbuf);

    k_torso<<<Bsz, 1024, 0, stream>>>(xx, ss, Win, b_in, wbuf,
                                      (const float4*)WlT, bl, lng, lnb, out);

    k_tf3<<<Bsz, 256, 0, stream>>>(xx, ss,
                                   WactB, bact, WqkvB, bqkv, WoB, bo,
                                   ln1g, ln1b, ln2g, ln2b,
                                   W1B, b1, W2B, b2,
                                   Wsc, bsc, out);
}

// Round 12
// 373.503 us; speedup vs baseline: 1.2692x; 1.2692x over previous
//
#include <hip/hip_runtime.h>
#include <hip/hip_bf16.h>
#include <string.h>

typedef __hip_bfloat16 bf16;
typedef __attribute__((ext_vector_type(8))) short short8;
typedef __attribute__((ext_vector_type(4))) float f32x4;

#define Bsz 512
#define S3  512
#define Tsz 16
#define Cc  128
#define TT  15
#define EPSv 1e-5f

__device__ __forceinline__ float ulo(unsigned u) { return __uint_as_float(u << 16); }
__device__ __forceinline__ float uhi(unsigned u) { return __uint_as_float(u & 0xffff0000u); }
__device__ __forceinline__ unsigned short f2bu(float v) {
    bf16 h = __float2bfloat16(v);
    unsigned short u; memcpy(&u, &h, 2); return u;
}
// fast RNE bf16 (no NaN path — inputs finite)
__device__ __forceinline__ unsigned short bfr16(float a) {
    unsigned u = __float_as_uint(a);
    u = u + 0x7fffu + ((u >> 16) & 1u);
    return (unsigned short)(u >> 16);
}
__device__ __forceinline__ unsigned fpack2(float a, float b) {
    unsigned ua = __float_as_uint(a), ub = __float_as_uint(b);
    ua = ua + 0x7fffu + ((ua >> 16) & 1u);
    ub = ub + 0x7fffu + ((ub >> 16) & 1u);
    return (ua >> 16) | (ub & 0xffff0000u);
}
__device__ __forceinline__ float dot4(float4 a, float4 b) {
    return a.x*b.x + a.y*b.y + a.z*b.z + a.w*b.w;
}

// ---------------------------------------------------------------------------
// k_tpack: src (NR x NK) row-major fp32 -> float4-packed k-major (Wl for base)
// ---------------------------------------------------------------------------
__global__ __launch_bounds__(256) void k_tpack(const float* __restrict__ src,
                                               float* __restrict__ dst,
                                               int NR, int NK)
{
    __shared__ float tile[32][33];
    int k0 = blockIdx.x * 32, r0 = blockIdx.y * 32;
    int lr = threadIdx.x >> 5, lk = threadIdx.x & 31;
    for (int i = lr; i < 32; i += 8)
        tile[i][lk] = src[(size_t)(r0 + i) * NK + k0 + lk];
    __syncthreads();
    int c = threadIdx.x & 31, k4 = threadIdx.x >> 5;
    float4 v;
    v.x = tile[c][k4 * 4 + 0]; v.y = tile[c][k4 * 4 + 1];
    v.z = tile[c][k4 * 4 + 2]; v.w = tile[c][k4 * 4 + 3];
    ((float4*)dst)[(size_t)(k0 / 4 + k4) * NR + r0 + c] = v;
}

// ---------------------------------------------------------------------------
// k_cvt5: all 5 transformer weights fp32 -> bf16 in one launch (contiguous dst)
// ---------------------------------------------------------------------------
__global__ __launch_bounds__(256) void k_cvt5(
    const float* __restrict__ s0, const float* __restrict__ s1,
    const float* __restrict__ s2, const float* __restrict__ s3,
    const float* __restrict__ s4, ushort* __restrict__ dst)
{
    int i = blockIdx.x * 256 + threadIdx.x;
    if (i >= 114688) return;
    const float* src; int rel;
    if (i < 16384)      { src = s0; rel = i; }
    else if (i < 40960) { src = s1; rel = i - 16384; }
    else if (i < 49152) { src = s2; rel = i - 40960; }
    else if (i < 81920) { src = s3; rel = i - 49152; }
    else                { src = s4; rel = i - 81920; }
    float4 v = ((const float4*)src)[rel];
    ushort4 o;
    o.x = f2bu(v.x); o.y = f2bu(v.y); o.z = f2bu(v.z); o.w = f2bu(v.w);
    ((ushort4*)dst)[i] = o;
}

// ---------------------------------------------------------------------------
// k_wgnn: Wl/Wr (3 layers, 128x128 fp32) -> bf16 MFMA-fragment-major,
// replicated 4x (one replica per m-pass) so k_torso's per-pass loads have
// genuinely distinct addresses (defeats LICM/CSE register hoisting).
// grid 24: rep = bi/6, w = bi%6 (0..2 Wl layer, 3..5 Wr layer).
// ---------------------------------------------------------------------------
__global__ __launch_bounds__(256) void k_wgnn(
    const float* __restrict__ Wl, const float* __restrict__ Wr,
    ushort* __restrict__ wbuf)
{
    int bi = blockIdx.x;
    int rep = bi / 6, w = bi % 6;
    const float* src = (w < 3) ? Wl + w * 16384 : Wr + (w - 3) * 16384;
    ushort* dst = wbuf + (size_t)(rep * 6 + w) * 16384;
    for (int item = threadIdx.x; item < 2048; item += 256) {
        int f = item >> 6, lane = item & 63;
        int t = f >> 2, ks = f & 3, ml = lane & 15, q = lane >> 4;
        int n = t * 16 + ml, kb = ks * 32 + q * 8;
        const float4* wr = (const float4*)(src + n * 128 + kb);
        float4 v0 = wr[0], v1 = wr[1];
        ushort4 o0, o1;
        o0.x = f2bu(v0.x); o0.y = f2bu(v0.y); o0.z = f2bu(v0.z); o0.w = f2bu(v0.w);
        o1.x = f2bu(v1.x); o1.y = f2bu(v1.y); o1.z = f2bu(v1.z); o1.w = f2bu(v1.w);
        ushort* dp = dst + (size_t)f * 512 + lane * 8;
        *(ushort4*)dp = o0;
        *(ushort4*)(dp + 4) = o1;
    }
}

// ---------------------------------------------------------------------------
// k_torso: fused init + 3 GNN layers + pool. 1024 threads (16 waves).
// Wave = (node-group g = wv>>1: 64 nodes, channel-half = wv&1: 64 ch).
// 4 sequential (nounroll) m-passes of 16 nodes, each reading its own wbuf
// replica -> only accR[4]+accL[4]=32 acc regs + ~8 transient B regs live.
// ---------------------------------------------------------------------------
__global__ __launch_bounds__(1024) void k_torso(
    const int* __restrict__ xx, const float* __restrict__ ss,
    const float* __restrict__ Win, const float* __restrict__ b_in,
    const ushort* __restrict__ wbuf,
    const float4* __restrict__ WlP, const float* __restrict__ blv,
    const float* __restrict__ lng, const float* __restrict__ lnb,
    float* __restrict__ out)
{
    __shared__ ushort X[512 * 136];      // 139264 B
    __shared__ float  mC[512];
    __shared__ float2 st2[512 * 2];      // row stats per half
    __shared__ float  sred[16 * 128];
    __shared__ float  ssc[128];
    __shared__ float  sbase[128];
    __shared__ float  gln[128], bln[128];
    __shared__ float  scnt[16];
    __shared__ float  invS;

    int b = blockIdx.x, tid = threadIdx.x;
    int wv = tid >> 6, lane = tid & 63;
    int ml = lane & 15, quad = lane >> 4;
    int half = wv & 1, g = wv >> 1;      // g 0..7 -> nodes [g*64, g*64+64)

    // ================= init =================
    {
        int ph = wv, cp = lane;
        int co0 = 2 * cp, co1 = 2 * cp + 1;
        const int* x0 = xx + (size_t)b * Tsz * S3;
        float f4c = ss[b] * (1.0f / 8.0f);
        float a0 = Win[co0*5+0], a1 = Win[co0*5+1], a2 = Win[co0*5+2], a3 = Win[co0*5+3];
        float c0 = Win[co1*5+0], c1 = Win[co1*5+1], c2 = Win[co1*5+2], c3 = Win[co1*5+3];
        float ba = b_in[co0] + f4c * Win[co0*5+4];
        float bc = b_in[co1] + f4c * Win[co1*5+4];
        float sp0 = 0.f, sp1 = 0.f; int cnt = 0;
        for (int node = ph; node < S3; node += 16) {
            int f0 = x0[node];
            float m = (f0 != 0) ? 1.f : 0.f;
            float ci = (float)(node >> 6) * (1.f / 7.f);
            float cj = (float)((node >> 3) & 7) * (1.f / 7.f);
            float ck = (float)(node & 7) * (1.f / 7.f);
            float ft = (float)f0 * 0.5f;
            float v0 = ba + ci * a0 + cj * a1 + ck * a2 + ft * a3;
            float v1 = bc + ci * c0 + cj * c1 + ck * c2 + ft * c3;
            ((unsigned*)(X + node * 136))[cp] = fpack2(v0, v1);
            sp0 += v0 * m; sp1 += v1 * m;
            cnt += (f0 != 0);
            if (cp == 0) mC[node] = m;
        }
        sred[ph * 128 + co0] = sp0;
        sred[ph * 128 + co1] = sp1;
        if (cp == 0) scnt[ph] = (float)cnt;
    }
    if (tid < 128) { gln[tid] = lng[tid]; bln[tid] = lnb[tid]; }
    __syncthreads();
    if (tid == 0) {
        float n = 0.f;
#pragma unroll
        for (int k = 0; k < 16; k++) n += scnt[k];
        invS = (n > 1.f) ? 1.f / (n - 1.f) : 0.f;
    }
    __syncthreads();
    if (tid < 128) {
        float s = 0.f;
#pragma unroll
        for (int k = 0; k < 16; k++) s += sred[k * 128 + tid];
        ssc[tid] = s * invS;
    }
    __syncthreads();
    if (tid < 128) {
        float a = blv[tid];
        for (int k4 = 0; k4 < 32; k4++)
            a += dot4(*(const float4*)(ssc + k4 * 4), WlP[k4 * 384 + tid]);
        sbase[tid] = a;
    }
    __syncthreads();

    // layer-invariant LN params for this wave's 4 channel tiles
    float gg[4], be[4];
#pragma unroll
    for (int t = 0; t < 4; t++) {
        gg[t] = gln[(half * 4 + t) * 16 + ml];
        be[t] = bln[(half * 4 + t) * 16 + ml];
    }

    // ================= 3 SAGE layers =================
    float inv = invS;
#pragma unroll 1
    for (int l = 0; l < 3; l++) {
        bool last = (l == 2);

        float sp[4];
#pragma unroll
        for (int t = 0; t < 4; t++) sp[t] = 0.f;

#pragma unroll 1
        for (int pass = 0; pass < 4; pass++) {
            int base = g * 64 + pass * 16;
            // per-pass replica -> addresses differ across passes (no LICM/CSE)
            const ushort* pWl = wbuf + (size_t)(pass * 6 + l) * 16384
                              + (size_t)(half * 16) * 512 + lane * 8;
            const ushort* pWr = pWl + (size_t)3 * 16384;

            f32x4 accR[4], accL[4];
#pragma unroll
            for (int t = 0; t < 4; t++) {
                accR[t] = (f32x4){0.f, 0.f, 0.f, 0.f};
                accL[t] = (f32x4){0.f, 0.f, 0.f, 0.f};
            }

            const ushort* xr = X + (base + ml) * 136 + quad * 8;
#pragma unroll
            for (int ks = 0; ks < 4; ks++) {
                short8 a = *(const short8*)(xr + ks * 32);
#pragma unroll
                for (int t = 0; t < 4; t++) {
                    int fo = (t * 4 + ks) * 512;
                    short8 br = *(const short8*)(pWr + fo);
                    short8 bl = *(const short8*)(pWl + fo);
                    accR[t] = __builtin_amdgcn_mfma_f32_16x16x32_bf16(a, br, accR[t], 0, 0, 0);
                    accL[t] = __builtin_amdgcn_mfma_f32_16x16x32_bf16(a, bl, accL[t], 0, 0, 0);
                }
            }

            // combine + relu in-place; partial row stats over this half's 64 ch
            float bse[4];
#pragma unroll
            for (int t = 0; t < 4; t++) bse[t] = sbase[(half * 4 + t) * 16 + ml];
#pragma unroll
            for (int r = 0; r < 4; r++) {
                int row = base + quad * 4 + r;
                float s = 0.f, q = 0.f;
#pragma unroll
                for (int t = 0; t < 4; t++) {
                    float v = fmaxf(accR[t][r] - inv * accL[t][r] + bse[t], 0.f);
                    accR[t][r] = v;
                    s += v; q += v * v;
                }
#pragma unroll
                for (int off = 1; off <= 8; off <<= 1) {
                    s += __shfl_xor(s, off, 64);
                    q += __shfl_xor(q, off, 64);
                }
                if (ml == 0) st2[row * 2 + half] = make_float2(s, q);
            }
            __syncthreads();

            // apply LN, store bf16, masked channel partial sums
#pragma unroll
            for (int r = 0; r < 4; r++) {
                int row = base + quad * 4 + r;
                float2 p0 = st2[row * 2];
                float2 p1 = st2[row * 2 + 1];
                float s = p0.x + p1.x, q = p0.y + p1.y;
                float mu = s * (1.f / 128.f);
                float rs = rsqrtf(q * (1.f / 128.f) - mu * mu + EPSv);
                float mrow = mC[row];
#pragma unroll
                for (int t = 0; t < 4; t++) {
                    float y = (accR[t][r] - mu) * rs * gg[t] + be[t];
                    if (last) y *= mrow;
                    else sp[t] += y * mrow;
                    X[row * 136 + (half * 4 + t) * 16 + ml] = bfr16(y);
                }
            }
        }

        if (!last) {
#pragma unroll
            for (int t = 0; t < 4; t++) {
                sp[t] += __shfl_xor(sp[t], 16, 64);
                sp[t] += __shfl_xor(sp[t], 32, 64);
            }
            if (quad == 0) {
#pragma unroll
                for (int t = 0; t < 4; t++) sred[wv * 64 + t * 16 + ml] = sp[t];
            }
            __syncthreads();
            if (tid < 128) {
                int hf = tid >> 6, tt = (tid >> 4) & 3, mm = tid & 15;
                float s = 0.f;
#pragma unroll
                for (int k = 0; k < 8; k++)
                    s += sred[(k * 2 + hf) * 64 + tt * 16 + mm];
                ssc[tid] = s * invS;
            }
            __syncthreads();
            if (tid < 128) {
                float a = blv[(l + 1) * 128 + tid];
                for (int k4 = 0; k4 < 32; k4++)
                    a += dot4(*(const float4*)(ssc + k4 * 4), WlP[k4 * 384 + (l + 1) * 128 + tid]);
                sbase[tid] = a;
            }
            __syncthreads();
        }
    }
    __syncthreads();

    // ================= pool: slice means, 4-channel vectorized =================
    if (tid < 768) {
        int c4 = tid & 31, p = tid >> 5;
        int axis = p >> 3, idx = p & 7;
        float4 sum = {0.f, 0.f, 0.f, 0.f};
        for (int t = 0; t < 64; t++) {
            int node;
            if (axis == 0)      node = idx * 64 + t;
            else if (axis == 1) node = (t >> 3) * 64 + idx * 8 + (t & 7);
            else                node = t * 8 + idx;
            uint2 pk = *(const uint2*)(X + node * 136 + c4 * 4);
            sum.x += ulo(pk.x);
            sum.y += uhi(pk.x);
            sum.z += ulo(pk.y);
            sum.w += uhi(pk.y);
        }
        float4 o;
        o.x = sum.x * (1.f / 64.f); o.y = sum.y * (1.f / 64.f);
        o.z = sum.z * (1.f / 64.f); o.w = sum.w * (1.f / 64.f);
        *(float4*)(out + (size_t)b * 26 * Cc + p * Cc + c4 * 4) = o;
    }
}

// ---------------------------------------------------------------------------
// k_tf3: transformer, bf16 MFMA GEMMs; q/k/v stored bf16 (~50 KB LDS)
// ---------------------------------------------------------------------------
__global__ __launch_bounds__(256) void k_tf3(
    const int* __restrict__ xx, const float* __restrict__ ss,
    const ushort* __restrict__ WactB, const float* __restrict__ bact,
    const ushort* __restrict__ WqkvB, const float* __restrict__ bqkv,
    const ushort* __restrict__ WoB, const float* __restrict__ bo,
    const float* __restrict__ ln1g, const float* __restrict__ ln1b,
    const float* __restrict__ ln2g, const float* __restrict__ ln2b,
    const ushort* __restrict__ W1B, const float* __restrict__ b1v,
    const ushort* __restrict__ W2B, const float* __restrict__ b2v,
    const float* __restrict__ Wsc, const float* __restrict__ bsc,
    float* __restrict__ out)
{
    __shared__ float  As[TT * 132];
    __shared__ ushort Qs[16 * 392];
    __shared__ ushort Ab[16 * 136];
    __shared__ ushort Hs[16 * 136];
    __shared__ ushort Fs[16 * 520];
    __shared__ float  Att[60 * 16];
    __shared__ float  mu_s[TT], rs_s[TT];

    int b = blockIdx.x, tid = threadIdx.x;
    int wv = tid >> 6, lane = tid & 63;
    int ml = lane & 15, quad = lane >> 4;

    const int* xa = xx + (size_t)b * Tsz * S3 + S3;
    for (int f = tid; f < TT * 512; f += 256) {
        int t = f >> 9, s = f & 511;
        Fs[t * 520 + s] = bfr16((float)xa[t * 512 + s]);
    }
    __syncthreads();

    {
        f32x4 acc[2];
#pragma unroll
        for (int i = 0; i < 2; i++) acc[i] = (f32x4){0.f, 0.f, 0.f, 0.f};
        const ushort* ar = Fs + ml * 520 + quad * 8;
        for (int ks = 0; ks < 16; ks++) {
            short8 a = *(const short8*)(ar + ks * 32);
#pragma unroll
            for (int i = 0; i < 2; i++) {
                int n0 = (wv * 2 + i) * 16;
                short8 bfr = *(const short8*)(WactB + (size_t)(n0 + ml) * 512 + quad * 8 + ks * 32);
                acc[i] = __builtin_amdgcn_mfma_f32_16x16x32_bf16(a, bfr, acc[i], 0, 0, 0);
            }
        }
#pragma unroll
        for (int i = 0; i < 2; i++) {
            int col = (wv * 2 + i) * 16 + ml;
            float bb = bact[col];
#pragma unroll
            for (int r = 0; r < 4; r++) {
                int row = quad * 4 + r;
                if (row < TT) As[row * 132 + col] = acc[i][r] + bb;
            }
        }
    }
    __syncthreads();

    for (int l = 0; l < 2; l++) {
        const float* bq  = bqkv + l * 384;
        const float* bol = bo + l * 128;
        const float* g1  = ln1g + l * 128; const float* be1 = ln1b + l * 128;
        const float* g2  = ln2g + l * 128; const float* be2 = ln2b + l * 128;
        const float* b1l = b1v + l * 512;  const float* b2l = b2v + l * 128;

        // LN1
        for (int r = wv; r < TT; r += 4) {
            float2 v = *(const float2*)(As + r * 132 + lane * 2);
            float s = v.x + v.y, q = v.x * v.x + v.y * v.y;
            for (int off = 32; off; off >>= 1) {
                s += __shfl_xor(s, off, 64);
                q += __shfl_xor(q, off, 64);
            }
            if (lane == 0) {
                float mu = s * (1.f / 128.f);
                mu_s[r] = mu;
                rs_s[r] = rsqrtf(q * (1.f / 128.f) - mu * mu + EPSv);
            }
        }
        __syncthreads();
        for (int f = tid; f < TT * 64; f += 256) {
            int t = f >> 6, cp = f & 63;
            float mu = mu_s[t], rs = rs_s[t];
            float x0 = (As[t * 132 + 2 * cp]     - mu) * rs * g1[2 * cp]     + be1[2 * cp];
            float x1 = (As[t * 132 + 2 * cp + 1] - mu) * rs * g1[2 * cp + 1] + be1[2 * cp + 1];
            ((unsigned*)(Ab + t * 136))[cp] = fpack2(x0, x1);
        }
        __syncthreads();

        // qkv (K=128, N=384) -> Qs bf16
        {
            short8 a[4];
            const ushort* ar = Ab + ml * 136 + quad * 8;
#pragma unroll
            for (int ks = 0; ks < 4; ks++) a[ks] = *(const short8*)(ar + ks * 32);
#pragma unroll
            for (int i = 0; i < 6; i++) {
                int n0 = (wv * 6 + i) * 16;
                f32x4 acc = (f32x4){0.f, 0.f, 0.f, 0.f};
                const ushort* wb = WqkvB + (size_t)(l * 384 + n0 + ml) * 128 + quad * 8;
#pragma unroll
                for (int ks = 0; ks < 4; ks++) {
                    short8 bfr = *(const short8*)(wb + ks * 32);
                    acc = __builtin_amdgcn_mfma_f32_16x16x32_bf16(a[ks], bfr, acc, 0, 0, 0);
                }
                int col = n0 + ml;
                float bb = bq[col];
#pragma unroll
                for (int r = 0; r < 4; r++) {
                    int row = quad * 4 + r;
                    if (row < TT) Qs[row * 392 + col] = bfr16(acc[r] + bb);
                }
            }
        }
        __syncthreads();

        // attention scores + softmax
        if (tid < 60) {
            int h = tid / 15, tq = tid % 15;
            const ushort* qp = Qs + tq * 392 + h * 32;
            float sc[TT];
            float mx = -1e30f;
#pragma unroll
            for (int tk = 0; tk < TT; tk++) {
                const ushort* kp = Qs + tk * 392 + 128 + h * 32;
                float d = 0.f;
#pragma unroll
                for (int u = 0; u < 32; u += 4) {
                    uint2 qa = *(const uint2*)(qp + u);
                    uint2 ka = *(const uint2*)(kp + u);
                    d += ulo(qa.x) * ulo(ka.x) + uhi(qa.x) * uhi(ka.x)
                       + ulo(qa.y) * ulo(ka.y) + uhi(qa.y) * uhi(ka.y);
                }
                d *= 0.17677669529663689f;
                sc[tk] = d; mx = fmaxf(mx, d);
            }
            float sum = 0.f;
#pragma unroll
            for (int tk = 0; tk < TT; tk++) { float e = __expf(sc[tk] - mx); sc[tk] = e; sum += e; }
            float r = 1.f / sum;
#pragma unroll
            for (int tk = 0; tk < TT; tk++) Att[tid * 16 + tk] = sc[tk] * r;
        }
        __syncthreads();

        // o = att @ v -> Hs (bf16)
        for (int f = tid; f < TT * 64; f += 256) {
            int t = f >> 6, cp = f & 63;
            int h = cp >> 4;
            const float* ap = Att + (h * 15 + t) * 16;
            const ushort* vp = Qs + 256 + 2 * cp;
            float a0 = 0.f, a1 = 0.f;
#pragma unroll
            for (int tk = 0; tk < TT; tk++) {
                float w = ap[tk];
                unsigned pk = *(const unsigned*)(vp + tk * 392);
                a0 += w * ulo(pk);
                a1 += w * uhi(pk);
            }
            ((unsigned*)(Hs + t * 136))[cp] = fpack2(a0, a1);
        }
        __syncthreads();

        // proj + residual
        {
            short8 a[4];
            const ushort* ar = Hs + ml * 136 + quad * 8;
#pragma unroll
            for (int ks = 0; ks < 4; ks++) a[ks] = *(const short8*)(ar + ks * 32);
#pragma unroll
            for (int i = 0; i < 2; i++) {
                int n0 = (wv * 2 + i) * 16;
                f32x4 acc = (f32x4){0.f, 0.f, 0.f, 0.f};
                const ushort* wb = WoB + (size_t)(l * 128 + n0 + ml) * 128 + quad * 8;
#pragma unroll
                for (int ks = 0; ks < 4; ks++) {
                    short8 bfr = *(const short8*)(wb + ks * 32);
                    acc = __builtin_amdgcn_mfma_f32_16x16x32_bf16(a[ks], bfr, acc, 0, 0, 0);
                }
                int col = n0 + ml;
                float bb = bol[col];
#pragma unroll
                for (int r = 0; r < 4; r++) {
                    int row = quad * 4 + r;
                    if (row < TT) As[row * 132 + col] += acc[r] + bb;
                }
            }
        }
        __syncthreads();

        // LN2
        for (int r = wv; r < TT; r += 4) {
            float2 v = *(const float2*)(As + r * 132 + lane * 2);
            float s = v.x + v.y, q = v.x * v.x + v.y * v.y;
            for (int off = 32; off; off >>= 1) {
                s += __shfl_xor(s, off, 64);
                q += __shfl_xor(q, off, 64);
            }
            if (lane == 0) {
                float mu = s * (1.f / 128.f);
                mu_s[r] = mu;
                rs_s[r] = rsqrtf(q * (1.f / 128.f) - mu * mu + EPSv);
            }
        }
        __syncthreads();
        for (int f = tid; f < TT * 64; f += 256) {
            int t = f >> 6, cp = f & 63;
            float mu = mu_s[t], rs = rs_s[t];
            float x0 = (As[t * 132 + 2 * cp]     - mu) * rs * g2[2 * cp]     + be2[2 * cp];
            float x1 = (As[t * 132 + 2 * cp + 1] - mu) * rs * g2[2 * cp + 1] + be2[2 * cp + 1];
            ((unsigned*)(Ab + t * 136))[cp] = fpack2(x0, x1);
        }
        __syncthreads();

        // ff1 (K=128, N=512)
        {
            short8 a[4];
            const ushort* ar = Ab + ml * 136 + quad * 8;
#pragma unroll
            for (int ks = 0; ks < 4; ks++) a[ks] = *(const short8*)(ar + ks * 32);
#pragma unroll
            for (int i = 0; i < 8; i++) {
                int n0 = (wv * 8 + i) * 16;
                f32x4 acc = (f32x4){0.f, 0.f, 0.f, 0.f};
                const ushort* wb = W1B + (size_t)(l * 512 + n0 + ml) * 128 + quad * 8;
#pragma unroll
                for (int ks = 0; ks < 4; ks++) {
                    short8 bfr = *(const short8*)(wb + ks * 32);
                    acc = __builtin_amdgcn_mfma_f32_16x16x32_bf16(a[ks], bfr, acc, 0, 0, 0);
                }
                int col = n0 + ml;
                float bb = b1l[col];
#pragma unroll
                for (int r = 0; r < 4; r++) {
                    int row = quad * 4 + r;
                    if (row < TT) Fs[row * 520 + col] = bfr16(fmaxf(acc[r] + bb, 0.f));
                }
            }
        }
        __syncthreads();

        // ff2 + residual (K=512, N=128)
        {
            f32x4 acc[2];
#pragma unroll
            for (int i = 0; i < 2; i++) acc[i] = (f32x4){0.f, 0.f, 0.f, 0.f};
            const ushort* ar = Fs + ml * 520 + quad * 8;
            for (int ks = 0; ks < 16; ks++) {
                short8 a = *(const short8*)(ar + ks * 32);
#pragma unroll
                for (int i = 0; i < 2; i++) {
                    int n0 = (wv * 2 + i) * 16;
                    short8 bfr = *(const short8*)(W2B + (size_t)(l * 128 + n0 + ml) * 512 + quad * 8 + ks * 32);
                    acc[i] = __builtin_amdgcn_mfma_f32_16x16x32_bf16(a, bfr, acc[i], 0, 0, 0);
                }
            }
#pragma unroll
            for (int i = 0; i < 2; i++) {
                int col = (wv * 2 + i) * 16 + ml;
                float bb = b2l[col];
#pragma unroll
                for (int r = 0; r < 4; r++) {
                    int row = quad * 4 + r;
                    if (row < TT) As[row * 132 + col] += acc[i][r] + bb;
                }
            }
        }
        __syncthreads();
    }

    if (tid < 128) {
        float s = 0.f;
#pragma unroll
        for (int t = 0; t < TT; t++) s += As[t * 132 + tid];
        out[(size_t)b * 26 * Cc + 24 * Cc + tid] = s * (1.f / 15.f);
    } else if (tid < 256) {
        int co = tid - 128;
        float v = ss[b] * Wsc[co] + bsc[co];
        out[(size_t)b * 26 * Cc + 25 * Cc + co] = fmaxf(v, 0.f);
    }
}

// ---------------------------------------------------------------------------
extern "C" void kernel_launch(void* const* d_in, const int* in_sizes, int n_in,
                              void* d_out, int out_size, void* d_ws, size_t ws_size,
                              hipStream_t stream)
{
    (void)in_sizes; (void)n_in; (void)out_size; (void)ws_size;
    const int*   xx   = (const int*)d_in[0];
    const float* ss   = (const float*)d_in[1];
    const float* Win  = (const float*)d_in[2];
    const float* b_in = (const float*)d_in[3];
    const float* Wl   = (const float*)d_in[4];
    const float* bl   = (const float*)d_in[5];
    const float* Wr   = (const float*)d_in[6];
    const float* lng  = (const float*)d_in[7];
    const float* lnb  = (const float*)d_in[8];
    const float* Wqkv = (const float*)d_in[9];
    const float* bqkv = (const float*)d_in[10];
    const float* Wo   = (const float*)d_in[11];
    const float* bo   = (const float*)d_in[12];
    const float* ln1g = (const float*)d_in[13];
    const float* ln1b = (const float*)d_in[14];
    const float* ln2g = (const float*)d_in[15];
    const float* ln2b = (const float*)d_in[16];
    const float* W1   = (const float*)d_in[17];
    const float* b1   = (const float*)d_in[18];
    const float* W2   = (const float*)d_in[19];
    const float* b2   = (const float*)d_in[20];
    const float* Wact = (const float*)d_in[21];
    const float* bact = (const float*)d_in[22];
    const float* Wsc  = (const float*)d_in[23];
    const float* bsc  = (const float*)d_in[24];
    float* out = (float*)d_out;

    char* ws = (char*)d_ws;
    size_t off = 0;
    float* WlT   = (float*)(ws + off);  off += 384 * 128 * 4;
    ushort* wbuf = (ushort*)(ws + off); off += (size_t)4 * 6 * 16384 * 2;   // 786 KB (4 replicas)
    ushort* WactB = (ushort*)(ws + off); off += 128 * 512 * 2;
    ushort* WqkvB = (ushort*)(ws + off); off += 768 * 128 * 2;
    ushort* WoB   = (ushort*)(ws + off); off += 256 * 128 * 2;
    ushort* W1B   = (ushort*)(ws + off); off += 1024 * 128 * 2;
    ushort* W2B   = (ushort*)(ws + off); off += 256 * 512 * 2;

    k_tpack<<<dim3(4, 12), 256, 0, stream>>>(Wl, WlT, 384, 128);
    k_cvt5<<<448, 256, 0, stream>>>(Wact, Wqkv, Wo, W1, W2, WactB);
    k_wgnn<<<24, 256, 0, stream>>>(Wl, Wr, wbuf);

    k_torso<<<Bsz, 1024, 0, stream>>>(xx, ss, Win, b_in, wbuf,
                                      (const float4*)WlT, bl, lng, lnb, out);

    k_tf3<<<Bsz, 256, 0, stream>>>(xx, ss,
                                   WactB, bact, WqkvB, bqkv, WoB, bo,
                                   ln1g, ln1b, ln2g, ln2b,
                                   W1B, b1, W2B, b2,
                                   Wsc, bsc, out);
}

// Round 13
// 342.921 us; speedup vs baseline: 1.3824x; 1.0892x over previous
//
#include <hip/hip_runtime.h>
#include <hip/hip_bf16.h>
#include <string.h>

typedef __hip_bfloat16 bf16;
typedef __attribute__((ext_vector_type(8))) short short8;
typedef __attribute__((ext_vector_type(4))) float f32x4;

#define Bsz 512
#define S3  512
#define Tsz 16
#define Cc  128
#define TT  15
#define EPSv 1e-5f

__device__ __forceinline__ float ulo(unsigned u) { return __uint_as_float(u << 16); }
__device__ __forceinline__ float uhi(unsigned u) { return __uint_as_float(u & 0xffff0000u); }
__device__ __forceinline__ unsigned short f2bu(float v) {
    bf16 h = __float2bfloat16(v);
    unsigned short u; memcpy(&u, &h, 2); return u;
}
// fast RNE bf16 (no NaN path — inputs finite)
__device__ __forceinline__ unsigned short bfr16(float a) {
    unsigned u = __float_as_uint(a);
    u = u + 0x7fffu + ((u >> 16) & 1u);
    return (unsigned short)(u >> 16);
}
__device__ __forceinline__ unsigned fpack2(float a, float b) {
    unsigned ua = __float_as_uint(a), ub = __float_as_uint(b);
    ua = ua + 0x7fffu + ((ua >> 16) & 1u);
    ub = ub + 0x7fffu + ((ub >> 16) & 1u);
    return (ua >> 16) | (ub & 0xffff0000u);
}
__device__ __forceinline__ float dot4(float4 a, float4 b) {
    return a.x*b.x + a.y*b.y + a.z*b.z + a.w*b.w;
}

// ---------------------------------------------------------------------------
// k_tpack: src (NR x NK) row-major fp32 -> float4-packed k-major (Wl for base)
// ---------------------------------------------------------------------------
__global__ __launch_bounds__(256) void k_tpack(const float* __restrict__ src,
                                               float* __restrict__ dst,
                                               int NR, int NK)
{
    __shared__ float tile[32][33];
    int k0 = blockIdx.x * 32, r0 = blockIdx.y * 32;
    int lr = threadIdx.x >> 5, lk = threadIdx.x & 31;
    for (int i = lr; i < 32; i += 8)
        tile[i][lk] = src[(size_t)(r0 + i) * NK + k0 + lk];
    __syncthreads();
    int c = threadIdx.x & 31, k4 = threadIdx.x >> 5;
    float4 v;
    v.x = tile[c][k4 * 4 + 0]; v.y = tile[c][k4 * 4 + 1];
    v.z = tile[c][k4 * 4 + 2]; v.w = tile[c][k4 * 4 + 3];
    ((float4*)dst)[(size_t)(k0 / 4 + k4) * NR + r0 + c] = v;
}

// ---------------------------------------------------------------------------
// k_cvt5: all 5 transformer weights fp32 -> bf16 in one launch (contiguous dst)
// ---------------------------------------------------------------------------
__global__ __launch_bounds__(256) void k_cvt5(
    const float* __restrict__ s0, const float* __restrict__ s1,
    const float* __restrict__ s2, const float* __restrict__ s3,
    const float* __restrict__ s4, ushort* __restrict__ dst)
{
    int i = blockIdx.x * 256 + threadIdx.x;
    if (i >= 114688) return;
    const float* src; int rel;
    if (i < 16384)      { src = s0; rel = i; }
    else if (i < 40960) { src = s1; rel = i - 16384; }
    else if (i < 49152) { src = s2; rel = i - 40960; }
    else if (i < 81920) { src = s3; rel = i - 49152; }
    else                { src = s4; rel = i - 81920; }
    float4 v = ((const float4*)src)[rel];
    ushort4 o;
    o.x = f2bu(v.x); o.y = f2bu(v.y); o.z = f2bu(v.z); o.w = f2bu(v.w);
    ((ushort4*)dst)[i] = o;
}

// ---------------------------------------------------------------------------
// k_wgnn: Wl/Wr (3 layers, 128x128 fp32) -> bf16 MFMA-fragment-major.
// grid 6: bi 0..2 = Wl layer, 3..5 = Wr layer.
// wbuf[bi*16384 + (t*4+ks)*512 + lane*8 + j], n=t*16+ml, k=ks*32+quad*8+j
// ---------------------------------------------------------------------------
__global__ __launch_bounds__(256) void k_wgnn(
    const float* __restrict__ Wl, const float* __restrict__ Wr,
    ushort* __restrict__ wbuf)
{
    int bi = blockIdx.x;
    const float* src = (bi < 3) ? Wl + bi * 16384 : Wr + (bi - 3) * 16384;
    ushort* dst = wbuf + (size_t)bi * 16384;
    for (int item = threadIdx.x; item < 2048; item += 256) {
        int f = item >> 6, lane = item & 63;
        int t = f >> 2, ks = f & 3, ml = lane & 15, q = lane >> 4;
        int n = t * 16 + ml, kb = ks * 32 + q * 8;
        const float4* wr = (const float4*)(src + n * 128 + kb);
        float4 v0 = wr[0], v1 = wr[1];
        ushort4 o0, o1;
        o0.x = f2bu(v0.x); o0.y = f2bu(v0.y); o0.z = f2bu(v0.z); o0.w = f2bu(v0.w);
        o1.x = f2bu(v1.x); o1.y = f2bu(v1.y); o1.z = f2bu(v1.z); o1.w = f2bu(v1.w);
        ushort* dp = dst + (size_t)f * 512 + lane * 8;
        *(ushort4*)dp = o0;
        *(ushort4*)(dp + 4) = o1;
    }
}

// ---------------------------------------------------------------------------
// k_torso: fused init + 3 GNN layers + pool. 512 threads (8 waves, 2/SIMD,
// 256-VGPR budget). Wave = (node-group g = wv>>1: 128 nodes, half = wv&1:
// 64 ch). Per layer: 32 weight fragments (128 VGPRs) loaded ONCE into
// registers, then 8 nounroll passes of 16 nodes with accR[4]+accL[4].
// ---------------------------------------------------------------------------
__global__ __launch_bounds__(512, 2) void k_torso(
    const int* __restrict__ xx, const float* __restrict__ ss,
    const float* __restrict__ Win, const float* __restrict__ b_in,
    const ushort* __restrict__ wbuf,
    const float4* __restrict__ WlP, const float* __restrict__ blv,
    const float* __restrict__ lng, const float* __restrict__ lnb,
    float* __restrict__ out)
{
    __shared__ ushort X[512 * 136];      // 139264 B
    __shared__ float  mC[512];
    __shared__ float2 st2[512 * 2];      // row stats per half (8 KB)
    __shared__ float  sred[8 * 128];     // init chan sums / layer chan sums
    __shared__ float  ssc[128];
    __shared__ float  sbase[128];
    __shared__ float  gln[128], bln[128];
    __shared__ float  scnt[8];
    __shared__ float  invS;

    int b = blockIdx.x, tid = threadIdx.x;
    int wv = tid >> 6, lane = tid & 63;
    int ml = lane & 15, quad = lane >> 4;
    int half = wv & 1, g = wv >> 1;      // g 0..3 -> nodes [g*128, g*128+128)

    // ================= init =================
    {
        int ph = wv, cp = lane;
        int co0 = 2 * cp, co1 = 2 * cp + 1;
        const int* x0 = xx + (size_t)b * Tsz * S3;
        float f4c = ss[b] * (1.0f / 8.0f);
        float a0 = Win[co0*5+0], a1 = Win[co0*5+1], a2 = Win[co0*5+2], a3 = Win[co0*5+3];
        float c0 = Win[co1*5+0], c1 = Win[co1*5+1], c2 = Win[co1*5+2], c3 = Win[co1*5+3];
        float ba = b_in[co0] + f4c * Win[co0*5+4];
        float bc = b_in[co1] + f4c * Win[co1*5+4];
        float sp0 = 0.f, sp1 = 0.f; int cnt = 0;
        for (int node = ph; node < S3; node += 8) {
            int f0 = x0[node];
            float m = (f0 != 0) ? 1.f : 0.f;
            float ci = (float)(node >> 6) * (1.f / 7.f);
            float cj = (float)((node >> 3) & 7) * (1.f / 7.f);
            float ck = (float)(node & 7) * (1.f / 7.f);
            float ft = (float)f0 * 0.5f;
            float v0 = ba + ci * a0 + cj * a1 + ck * a2 + ft * a3;
            float v1 = bc + ci * c0 + cj * c1 + ck * c2 + ft * c3;
            ((unsigned*)(X + node * 136))[cp] = fpack2(v0, v1);
            sp0 += v0 * m; sp1 += v1 * m;
            cnt += (f0 != 0);
            if (cp == 0) mC[node] = m;
        }
        sred[ph * 128 + co0] = sp0;
        sred[ph * 128 + co1] = sp1;
        if (cp == 0) scnt[ph] = (float)cnt;
    }
    if (tid < 128) { gln[tid] = lng[tid]; bln[tid] = lnb[tid]; }
    __syncthreads();
    if (tid == 0) {
        float n = 0.f;
#pragma unroll
        for (int k = 0; k < 8; k++) n += scnt[k];
        invS = (n > 1.f) ? 1.f / (n - 1.f) : 0.f;
    }
    __syncthreads();
    if (tid < 128) {
        float s = 0.f;
#pragma unroll
        for (int k = 0; k < 8; k++) s += sred[k * 128 + tid];
        ssc[tid] = s * invS;
    }
    __syncthreads();
    if (tid < 128) {
        float a = blv[tid];
        for (int k4 = 0; k4 < 32; k4++)
            a += dot4(*(const float4*)(ssc + k4 * 4), WlP[k4 * 384 + tid]);
        sbase[tid] = a;
    }
    __syncthreads();

    // layer-invariant LN params for this wave's 4 channel tiles
    float gg[4], be[4];
#pragma unroll
    for (int t = 0; t < 4; t++) {
        gg[t] = gln[(half * 4 + t) * 16 + ml];
        be[t] = bln[(half * 4 + t) * 16 + ml];
    }

    // ================= 3 SAGE layers =================
    float inv = invS;
#pragma unroll 1
    for (int l = 0; l < 3; l++) {
        bool last = (l == 2);

        // load this wave's weight slice ONCE into registers (32 frags = 128 VGPRs)
        short8 wfl[16], wfr[16];
        {
            const ushort* pWl = wbuf + (size_t)l * 16384 + lane * 8;
            const ushort* pWr = pWl + (size_t)3 * 16384;
#pragma unroll
            for (int t = 0; t < 4; t++)
#pragma unroll
                for (int ks = 0; ks < 4; ks++) {
                    int fo = ((half * 4 + t) * 4 + ks) * 512;
                    wfl[t * 4 + ks] = *(const short8*)(pWl + fo);
                    wfr[t * 4 + ks] = *(const short8*)(pWr + fo);
                }
        }

        float sp[4];
#pragma unroll
        for (int t = 0; t < 4; t++) sp[t] = 0.f;

#pragma unroll 1
        for (int pass = 0; pass < 8; pass++) {
            int base = g * 128 + pass * 16;

            f32x4 accR[4], accL[4];
#pragma unroll
            for (int t = 0; t < 4; t++) {
                accR[t] = (f32x4){0.f, 0.f, 0.f, 0.f};
                accL[t] = (f32x4){0.f, 0.f, 0.f, 0.f};
            }

            const ushort* xr = X + (base + ml) * 136 + quad * 8;
#pragma unroll
            for (int ks = 0; ks < 4; ks++) {
                short8 a = *(const short8*)(xr + ks * 32);
#pragma unroll
                for (int t = 0; t < 4; t++) {
                    accR[t] = __builtin_amdgcn_mfma_f32_16x16x32_bf16(a, wfr[t * 4 + ks], accR[t], 0, 0, 0);
                    accL[t] = __builtin_amdgcn_mfma_f32_16x16x32_bf16(a, wfl[t * 4 + ks], accL[t], 0, 0, 0);
                }
            }

            // combine + relu in-place; partial row stats over this half's 64 ch
            float bse[4];
#pragma unroll
            for (int t = 0; t < 4; t++) bse[t] = sbase[(half * 4 + t) * 16 + ml];
#pragma unroll
            for (int r = 0; r < 4; r++) {
                int row = base + quad * 4 + r;
                float s = 0.f, q = 0.f;
#pragma unroll
                for (int t = 0; t < 4; t++) {
                    float v = fmaxf(accR[t][r] - inv * accL[t][r] + bse[t], 0.f);
                    accR[t][r] = v;
                    s += v; q += v * v;
                }
#pragma unroll
                for (int off = 1; off <= 8; off <<= 1) {
                    s += __shfl_xor(s, off, 64);
                    q += __shfl_xor(q, off, 64);
                }
                if (ml == 0) st2[row * 2 + half] = make_float2(s, q);
            }
            __syncthreads();

            // apply LN, store bf16, masked channel partial sums
#pragma unroll
            for (int r = 0; r < 4; r++) {
                int row = base + quad * 4 + r;
                float2 p0 = st2[row * 2];
                float2 p1 = st2[row * 2 + 1];
                float s = p0.x + p1.x, q = p0.y + p1.y;
                float mu = s * (1.f / 128.f);
                float rs = rsqrtf(q * (1.f / 128.f) - mu * mu + EPSv);
                float mrow = mC[row];
#pragma unroll
                for (int t = 0; t < 4; t++) {
                    float y = (accR[t][r] - mu) * rs * gg[t] + be[t];
                    if (last) y *= mrow;
                    else sp[t] += y * mrow;
                    X[row * 136 + (half * 4 + t) * 16 + ml] = bfr16(y);
                }
            }
        }

        if (!last) {
#pragma unroll
            for (int t = 0; t < 4; t++) {
                sp[t] += __shfl_xor(sp[t], 16, 64);
                sp[t] += __shfl_xor(sp[t], 32, 64);
            }
            if (quad == 0) {
#pragma unroll
                for (int t = 0; t < 4; t++) sred[wv * 64 + t * 16 + ml] = sp[t];
            }
            __syncthreads();
            if (tid < 128) {
                int hf = tid >> 6, tt = (tid >> 4) & 3, mm = tid & 15;
                float s = 0.f;
#pragma unroll
                for (int k = 0; k < 4; k++)
                    s += sred[(k * 2 + hf) * 64 + tt * 16 + mm];
                ssc[tid] = s * invS;
            }
            __syncthreads();
            if (tid < 128) {
                float a = blv[(l + 1) * 128 + tid];
                for (int k4 = 0; k4 < 32; k4++)
                    a += dot4(*(const float4*)(ssc + k4 * 4), WlP[k4 * 384 + (l + 1) * 128 + tid]);
                sbase[tid] = a;
            }
            __syncthreads();
        }
    }
    __syncthreads();

    // ================= pool: slice means, 4-channel vectorized =================
    for (int f = tid; f < 768; f += 512) {
        int c4 = f & 31, p = f >> 5;
        int axis = p >> 3, idx = p & 7;
        float4 sum = {0.f, 0.f, 0.f, 0.f};
        for (int t = 0; t < 64; t++) {
            int node;
            if (axis == 0)      node = idx * 64 + t;
            else if (axis == 1) node = (t >> 3) * 64 + idx * 8 + (t & 7);
            else                node = t * 8 + idx;
            uint2 pk = *(const uint2*)(X + node * 136 + c4 * 4);
            sum.x += ulo(pk.x);
            sum.y += uhi(pk.x);
            sum.z += ulo(pk.y);
            sum.w += uhi(pk.y);
        }
        float4 o;
        o.x = sum.x * (1.f / 64.f); o.y = sum.y * (1.f / 64.f);
        o.z = sum.z * (1.f / 64.f); o.w = sum.w * (1.f / 64.f);
        *(float4*)(out + (size_t)b * 26 * Cc + p * Cc + c4 * 4) = o;
    }
}

// ---------------------------------------------------------------------------
// k_tf3: transformer, bf16 MFMA GEMMs; q/k/v stored bf16 (~50 KB LDS)
// ---------------------------------------------------------------------------
__global__ __launch_bounds__(256) void k_tf3(
    const int* __restrict__ xx, const float* __restrict__ ss,
    const ushort* __restrict__ WactB, const float* __restrict__ bact,
    const ushort* __restrict__ WqkvB, const float* __restrict__ bqkv,
    const ushort* __restrict__ WoB, const float* __restrict__ bo,
    const float* __restrict__ ln1g, const float* __restrict__ ln1b,
    const float* __restrict__ ln2g, const float* __restrict__ ln2b,
    const ushort* __restrict__ W1B, const float* __restrict__ b1v,
    const ushort* __restrict__ W2B, const float* __restrict__ b2v,
    const float* __restrict__ Wsc, const float* __restrict__ bsc,
    float* __restrict__ out)
{
    __shared__ float  As[TT * 132];
    __shared__ ushort Qs[16 * 392];
    __shared__ ushort Ab[16 * 136];
    __shared__ ushort Hs[16 * 136];
    __shared__ ushort Fs[16 * 520];
    __shared__ float  Att[60 * 16];
    __shared__ float  mu_s[TT], rs_s[TT];

    int b = blockIdx.x, tid = threadIdx.x;
    int wv = tid >> 6, lane = tid & 63;
    int ml = lane & 15, quad = lane >> 4;

    const int* xa = xx + (size_t)b * Tsz * S3 + S3;
    for (int f = tid; f < TT * 512; f += 256) {
        int t = f >> 9, s = f & 511;
        Fs[t * 520 + s] = bfr16((float)xa[t * 512 + s]);
    }
    __syncthreads();

    {
        f32x4 acc[2];
#pragma unroll
        for (int i = 0; i < 2; i++) acc[i] = (f32x4){0.f, 0.f, 0.f, 0.f};
        const ushort* ar = Fs + ml * 520 + quad * 8;
        for (int ks = 0; ks < 16; ks++) {
            short8 a = *(const short8*)(ar + ks * 32);
#pragma unroll
            for (int i = 0; i < 2; i++) {
                int n0 = (wv * 2 + i) * 16;
                short8 bfr = *(const short8*)(WactB + (size_t)(n0 + ml) * 512 + quad * 8 + ks * 32);
                acc[i] = __builtin_amdgcn_mfma_f32_16x16x32_bf16(a, bfr, acc[i], 0, 0, 0);
            }
        }
#pragma unroll
        for (int i = 0; i < 2; i++) {
            int col = (wv * 2 + i) * 16 + ml;
            float bb = bact[col];
#pragma unroll
            for (int r = 0; r < 4; r++) {
                int row = quad * 4 + r;
                if (row < TT) As[row * 132 + col] = acc[i][r] + bb;
            }
        }
    }
    __syncthreads();

    for (int l = 0; l < 2; l++) {
        const float* bq  = bqkv + l * 384;
        const float* bol = bo + l * 128;
        const float* g1  = ln1g + l * 128; const float* be1 = ln1b + l * 128;
        const float* g2  = ln2g + l * 128; const float* be2 = ln2b + l * 128;
        const float* b1l = b1v + l * 512;  const float* b2l = b2v + l * 128;

        // LN1
        for (int r = wv; r < TT; r += 4) {
            float2 v = *(const float2*)(As + r * 132 + lane * 2);
            float s = v.x + v.y, q = v.x * v.x + v.y * v.y;
            for (int off = 32; off; off >>= 1) {
                s += __shfl_xor(s, off, 64);
                q += __shfl_xor(q, off, 64);
            }
            if (lane == 0) {
                float mu = s * (1.f / 128.f);
                mu_s[r] = mu;
                rs_s[r] = rsqrtf(q * (1.f / 128.f) - mu * mu + EPSv);
            }
        }
        __syncthreads();
        for (int f = tid; f < TT * 64; f += 256) {
            int t = f >> 6, cp = f & 63;
            float mu = mu_s[t], rs = rs_s[t];
            float x0 = (As[t * 132 + 2 * cp]     - mu) * rs * g1[2 * cp]     + be1[2 * cp];
            float x1 = (As[t * 132 + 2 * cp + 1] - mu) * rs * g1[2 * cp + 1] + be1[2 * cp + 1];
            ((unsigned*)(Ab + t * 136))[cp] = fpack2(x0, x1);
        }
        __syncthreads();

        // qkv (K=128, N=384) -> Qs bf16
        {
            short8 a[4];
            const ushort* ar = Ab + ml * 136 + quad * 8;
#pragma unroll
            for (int ks = 0; ks < 4; ks++) a[ks] = *(const short8*)(ar + ks * 32);
#pragma unroll
            for (int i = 0; i < 6; i++) {
                int n0 = (wv * 6 + i) * 16;
                f32x4 acc = (f32x4){0.f, 0.f, 0.f, 0.f};
                const ushort* wb = WqkvB + (size_t)(l * 384 + n0 + ml) * 128 + quad * 8;
#pragma unroll
                for (int ks = 0; ks < 4; ks++) {
                    short8 bfr = *(const short8*)(wb + ks * 32);
                    acc = __builtin_amdgcn_mfma_f32_16x16x32_bf16(a[ks], bfr, acc, 0, 0, 0);
                }
                int col = n0 + ml;
                float bb = bq[col];
#pragma unroll
                for (int r = 0; r < 4; r++) {
                    int row = quad * 4 + r;
                    if (row < TT) Qs[row * 392 + col] = bfr16(acc[r] + bb);
                }
            }
        }
        __syncthreads();

        // attention scores + softmax
        if (tid < 60) {
            int h = tid / 15, tq = tid % 15;
            const ushort* qp = Qs + tq * 392 + h * 32;
            float sc[TT];
            float mx = -1e30f;
#pragma unroll
            for (int tk = 0; tk < TT; tk++) {
                const ushort* kp = Qs + tk * 392 + 128 + h * 32;
                float d = 0.f;
#pragma unroll
                for (int u = 0; u < 32; u += 4) {
                    uint2 qa = *(const uint2*)(qp + u);
                    uint2 ka = *(const uint2*)(kp + u);
                    d += ulo(qa.x) * ulo(ka.x) + uhi(qa.x) * uhi(ka.x)
                       + ulo(qa.y) * ulo(ka.y) + uhi(qa.y) * uhi(ka.y);
                }
                d *= 0.17677669529663689f;
                sc[tk] = d; mx = fmaxf(mx, d);
            }
            float sum = 0.f;
#pragma unroll
            for (int tk = 0; tk < TT; tk++) { float e = __expf(sc[tk] - mx); sc[tk] = e; sum += e; }
            float r = 1.f / sum;
#pragma unroll
            for (int tk = 0; tk < TT; tk++) Att[tid * 16 + tk] = sc[tk] * r;
        }
        __syncthreads();

        // o = att @ v -> Hs (bf16)
        for (int f = tid; f < TT * 64; f += 256) {
            int t = f >> 6, cp = f & 63;
            int h = cp >> 4;
            const float* ap = Att + (h * 15 + t) * 16;
            const ushort* vp = Qs + 256 + 2 * cp;
            float a0 = 0.f, a1 = 0.f;
#pragma unroll
            for (int tk = 0; tk < TT; tk++) {
                float w = ap[tk];
                unsigned pk = *(const unsigned*)(vp + tk * 392);
                a0 += w * ulo(pk);
                a1 += w * uhi(pk);
            }
            ((unsigned*)(Hs + t * 136))[cp] = fpack2(a0, a1);
        }
        __syncthreads();

        // proj + residual
        {
            short8 a[4];
            const ushort* ar = Hs + ml * 136 + quad * 8;
#pragma unroll
            for (int ks = 0; ks < 4; ks++) a[ks] = *(const short8*)(ar + ks * 32);
#pragma unroll
            for (int i = 0; i < 2; i++) {
                int n0 = (wv * 2 + i) * 16;
                f32x4 acc = (f32x4){0.f, 0.f, 0.f, 0.f};
                const ushort* wb = WoB + (size_t)(l * 128 + n0 + ml) * 128 + quad * 8;
#pragma unroll
                for (int ks = 0; ks < 4; ks++) {
                    short8 bfr = *(const short8*)(wb + ks * 32);
                    acc = __builtin_amdgcn_mfma_f32_16x16x32_bf16(a[ks], bfr, acc, 0, 0, 0);
                }
                int col = n0 + ml;
                float bb = bol[col];
#pragma unroll
                for (int r = 0; r < 4; r++) {
                    int row = quad * 4 + r;
                    if (row < TT) As[row * 132 + col] += acc[r] + bb;
                }
            }
        }
        __syncthreads();

        // LN2
        for (int r = wv; r < TT; r += 4) {
            float2 v = *(const float2*)(As + r * 132 + lane * 2);
            float s = v.x + v.y, q = v.x * v.x + v.y * v.y;
            for (int off = 32; off; off >>= 1) {
                s += __shfl_xor(s, off, 64);
                q += __shfl_xor(q, off, 64);
            }
            if (lane == 0) {
                float mu = s * (1.f / 128.f);
                mu_s[r] = mu;
                rs_s[r] = rsqrtf(q * (1.f / 128.f) - mu * mu + EPSv);
            }
        }
        __syncthreads();
        for (int f = tid; f < TT * 64; f += 256) {
            int t = f >> 6, cp = f & 63;
            float mu = mu_s[t], rs = rs_s[t];
            float x0 = (As[t * 132 + 2 * cp]     - mu) * rs * g2[2 * cp]     + be2[2 * cp];
            float x1 = (As[t * 132 + 2 * cp + 1] - mu) * rs * g2[2 * cp + 1] + be2[2 * cp + 1];
            ((unsigned*)(Ab + t * 136))[cp] = fpack2(x0, x1);
        }
        __syncthreads();

        // ff1 (K=128, N=512)
        {
            short8 a[4];
            const ushort* ar = Ab + ml * 136 + quad * 8;
#pragma unroll
            for (int ks = 0; ks < 4; ks++) a[ks] = *(const short8*)(ar + ks * 32);
#pragma unroll
            for (int i = 0; i < 8; i++) {
                int n0 = (wv * 8 + i) * 16;
                f32x4 acc = (f32x4){0.f, 0.f, 0.f, 0.f};
                const ushort* wb = W1B + (size_t)(l * 512 + n0 + ml) * 128 + quad * 8;
#pragma unroll
                for (int ks = 0; ks < 4; ks++) {
                    short8 bfr = *(const short8*)(wb + ks * 32);
                    acc = __builtin_amdgcn_mfma_f32_16x16x32_bf16(a[ks], bfr, acc, 0, 0, 0);
                }
                int col = n0 + ml;
                float bb = b1l[col];
#pragma unroll
                for (int r = 0; r < 4; r++) {
                    int row = quad * 4 + r;
                    if (row < TT) Fs[row * 520 + col] = bfr16(fmaxf(acc[r] + bb, 0.f));
                }
            }
        }
        __syncthreads();

        // ff2 + residual (K=512, N=128)
        {
            f32x4 acc[2];
#pragma unroll
            for (int i = 0; i < 2; i++) acc[i] = (f32x4){0.f, 0.f, 0.f, 0.f};
            const ushort* ar = Fs + ml * 520 + quad * 8;
            for (int ks = 0; ks < 16; ks++) {
                short8 a = *(const short8*)(ar + ks * 32);
#pragma unroll
                for (int i = 0; i < 2; i++) {
                    int n0 = (wv * 2 + i) * 16;
                    short8 bfr = *(const short8*)(W2B + (size_t)(l * 128 + n0 + ml) * 512 + quad * 8 + ks * 32);
                    acc[i] = __builtin_amdgcn_mfma_f32_16x16x32_bf16(a, bfr, acc[i], 0, 0, 0);
                }
            }
#pragma unroll
            for (int i = 0; i < 2; i++) {
                int col = (wv * 2 + i) * 16 + ml;
                float bb = b2l[col];
#pragma unroll
                for (int r = 0; r < 4; r++) {
                    int row = quad * 4 + r;
                    if (row < TT) As[row * 132 + col] += acc[i][r] + bb;
                }
            }
        }
        __syncthreads();
    }

    if (tid < 128) {
        float s = 0.f;
#pragma unroll
        for (int t = 0; t < TT; t++) s += As[t * 132 + tid];
        out[(size_t)b * 26 * Cc + 24 * Cc + tid] = s * (1.f / 15.f);
    } else if (tid < 256) {
        int co = tid - 128;
        float v = ss[b] * Wsc[co] + bsc[co];
        out[(size_t)b * 26 * Cc + 25 * Cc + co] = fmaxf(v, 0.f);
    }
}

// ---------------------------------------------------------------------------
extern "C" void kernel_launch(void* const* d_in, const int* in_sizes, int n_in,
                              void* d_out, int out_size, void* d_ws, size_t ws_size,
                              hipStream_t stream)
{
    (void)in_sizes; (void)n_in; (void)out_size; (void)ws_size;
    const int*   xx   = (const int*)d_in[0];
    const float* ss   = (const float*)d_in[1];
    const float* Win  = (const float*)d_in[2];
    const float* b_in = (const float*)d_in[3];
    const float* Wl   = (const float*)d_in[4];
    const float* bl   = (const float*)d_in[5];
    const float* Wr   = (const float*)d_in[6];
    const float* lng  = (const float*)d_in[7];
    const float* lnb  = (const float*)d_in[8];
    const float* Wqkv = (const float*)d_in[9];
    const float* bqkv = (const float*)d_in[10];
    const float* Wo   = (const float*)d_in[11];
    const float* bo   = (const float*)d_in[12];
    const float* ln1g = (const float*)d_in[13];
    const float* ln1b = (const float*)d_in[14];
    const float* ln2g = (const float*)d_in[15];
    const float* ln2b = (const float*)d_in[16];
    const float* W1   = (const float*)d_in[17];
    const float* b1   = (const float*)d_in[18];
    const float* W2   = (const float*)d_in[19];
    const float* b2   = (const float*)d_in[20];
    const float* Wact = (const float*)d_in[21];
    const float* bact = (const float*)d_in[22];
    const float* Wsc  = (const float*)d_in[23];
    const float* bsc  = (const float*)d_in[24];
    float* out = (float*)d_out;

    char* ws = (char*)d_ws;
    size_t off = 0;
    float* WlT   = (float*)(ws + off);  off += 384 * 128 * 4;
    ushort* wbuf = (ushort*)(ws + off); off += 6 * 16384 * 2;      // 196.6 KB
    ushort* WactB = (ushort*)(ws + off); off += 128 * 512 * 2;
    ushort* WqkvB = (ushort*)(ws + off); off += 768 * 128 * 2;
    ushort* WoB   = (ushort*)(ws + off); off += 256 * 128 * 2;
    ushort* W1B   = (ushort*)(ws + off); off += 1024 * 128 * 2;
    ushort* W2B   = (ushort*)(ws + off); off += 256 * 512 * 2;

    k_tpack<<<dim3(4, 12), 256, 0, stream>>>(Wl, WlT, 384, 128);
    k_cvt5<<<448, 256, 0, stream>>>(Wact, Wqkv, Wo, W1, W2, WactB);
    k_wgnn<<<6, 256, 0, stream>>>(Wl, Wr, wbuf);

    k_torso<<<Bsz, 512, 0, stream>>>(xx, ss, Win, b_in, wbuf,
                                     (const float4*)WlT, bl, lng, lnb, out);

    k_tf3<<<Bsz, 256, 0, stream>>>(xx, ss,
                                   WactB, bact, WqkvB, bqkv, WoB, bo,
                                   ln1g, ln1b, ln2g, ln2b,
                                   W1B, b1, W2B, b2,
                                   Wsc, bsc, out);
}